// Round 3
// baseline (110.186 us; speedup 1.0000x reference)
//
#include <hip/hip_runtime.h>

#define EPS_F 1e-6f
#define S_DIM 768
#define W_DIM 32

__global__ __launch_bounds__(256) void cope_fire_kernel(
    const float* __restrict__ attn,   // (H*S, S)
    const float* __restrict__ W_in,   // (32,1)
    const float* __restrict__ b_in,   // (32,)
    const float* __restrict__ W_out,  // (H,32)
    const float* __restrict__ b_out,  // (H,)
    const float* __restrict__ c_p,
    const float* __restrict__ Lm_p,
    const float* __restrict__ iL_p,
    float* __restrict__ out)
{
    const int row = blockIdx.x;        // 0 .. H*S-1
    const int h   = row / S_DIM;       // block-uniform
    const int t   = threadIdx.x;
    const int lane = t & 63;
    const int wave = t >> 6;

    __shared__ float s_wsum[12];       // 3 segments x 4 waves

    const float* rowp = attn + (size_t)row * S_DIM;
    const float c   = c_p[0];                      // uniform -> s_load
    const float thr = fabsf(Lm_p[0] * iL_p[0]);    // uniform
    const float bo  = b_out[h];                    // uniform

    // Load 3 coalesced strided elements; sigmoid via v_exp + v_rcp.
    float g[3];
#pragma unroll
    for (int s = 0; s < 3; s++) {
        float x = rowp[s * 256 + t];
        g[s] = __builtin_amdgcn_rcpf(1.0f + __expf(-x));
    }

    // Per-segment inclusive block scan (wave shuffle scan + wave-sum combine).
    float incl[3];
#pragma unroll
    for (int s = 0; s < 3; s++) {
        float x = g[s];
#pragma unroll
        for (int d = 1; d < 64; d <<= 1) {
            float y = __shfl_up(x, d, 64);
            if (lane >= d) x += y;
        }
        if (lane == 63) s_wsum[s * 4 + wave] = x;
        incl[s] = x;
    }
    __syncthreads();

    float segtot[3];
#pragma unroll
    for (int s = 0; s < 3; s++) {
        float w0 = s_wsum[s * 4 + 0];
        float w1 = s_wsum[s * 4 + 1];
        float w2 = s_wsum[s * 4 + 2];
        float w3 = s_wsum[s * 4 + 3];
        float woff = 0.0f;
        if (wave > 0) woff += w0;
        if (wave > 1) woff += w1;
        if (wave > 2) woff += w2;
        incl[s] += woff;
        segtot[s] = w0 + w1 + w2 + w3;
    }
    // Stitch segments into full-row inclusive prefix.
    const float off1  = segtot[0];
    const float off2  = segtot[0] + segtot[1];
    const float total = off2 + segtot[2];
    incl[1] += off1;
    incl[2] += off2;

    // Row-constant denominator: max_pos == pos[j=0] == total row sum.
    const float den = __logf(fabsf(c * fminf(total, thr)) + 1.0f) + EPS_F;
    const float inv_den = __builtin_amdgcn_rcpf(den);

    // dist per element (dist-space keeps weight operands row-independent,
    // so they can live in SGPRs — loaded below with uniform indices).
    float dist[3];
#pragma unroll
    for (int s = 0; s < 3; s++) {
        float pos = total - incl[s] + g[s];          // suffix sum
        dist[s] = __logf(fabsf(c * pos) + 1.0f) * inv_den;
    }

    // ---- W-contraction: weights as block-uniform scalar (SGPR) loads. ----
    float acc0 = bo, acc1 = bo, acc2 = bo;
    const float* woutp = W_out + h * W_DIM;          // block-uniform base
#pragma unroll
    for (int w = 0; w < W_DIM; w++) {
        const float w1v = W_in[w];     // s_load (uniform, const index)
        const float bv  = b_in[w];     // s_load
        const float ov  = woutp[w];    // s_load
        float h0 = fmaxf(fmaf(dist[0], w1v, bv), 0.0f);
        float h1 = fmaxf(fmaf(dist[1], w1v, bv), 0.0f);
        float h2 = fmaxf(fmaf(dist[2], w1v, bv), 0.0f);
        acc0 = fmaf(h0, ov, acc0);
        acc1 = fmaf(h1, ov, acc1);
        acc2 = fmaf(h2, ov, acc2);
    }

    float* outp = out + (size_t)row * S_DIM;
    outp[t]       = acc0;
    outp[256 + t] = acc1;
    outp[512 + t] = acc2;
}

extern "C" void kernel_launch(void* const* d_in, const int* in_sizes, int n_in,
                              void* d_out, int out_size, void* d_ws, size_t ws_size,
                              hipStream_t stream) {
    const float* attn  = (const float*)d_in[0];
    const float* W_in  = (const float*)d_in[1];
    const float* b_in  = (const float*)d_in[2];
    const float* W_out = (const float*)d_in[3];
    const float* b_out = (const float*)d_in[4];
    const float* c_p   = (const float*)d_in[5];
    const float* Lm_p  = (const float*)d_in[6];
    const float* iL_p  = (const float*)d_in[7];
    float* out = (float*)d_out;

    const int H = 12;
    const int rows = H * S_DIM;   // 9216 blocks
    cope_fire_kernel<<<rows, 256, 0, stream>>>(
        attn, W_in, b_in, W_out, b_out, c_p, Lm_p, iL_p, out);
}

// Round 4
// 102.820 us; speedup vs baseline: 1.0716x; 1.0716x over previous
//
#include <hip/hip_runtime.h>
#include <math.h>

#define EPS_F 1e-6f
#define S_DIM 768
#define W_DIM 32
#define H_DIM 12
#define NK 33   // intervals = W_DIM + 1

// ws float layout:
//   [0 .. 32)                      sorted hinge values (ascending)
//   [32 + h*2*NK + 2k]  = A_k(h)   (slope)
//   [32 + h*2*NK + 2k+1]= B_k(h)   (intercept, includes b_out[h])

// ---------------- setup: build sorted hinges + per-(h,k) PWL tables ----------
__global__ __launch_bounds__(512) void cope_setup_kernel(
    const float* __restrict__ W_in, const float* __restrict__ b_in,
    const float* __restrict__ W_out, const float* __restrict__ b_out,
    float* __restrict__ ws)
{
    __shared__ float th[W_DIM];
    __shared__ int   rk[W_DIM];
    const int t = threadIdx.x;

    if (t < W_DIM) {
        float w1 = W_in[t], b = b_in[t];
        th[t] = (w1 != 0.0f) ? (-b / w1) : __builtin_inff();
    }
    __syncthreads();

    if (t < W_DIM) {
        float mine = th[t];
        int r = 0;
        for (int v = 0; v < W_DIM; v++) {
            float o = th[v];
            if (o < mine || (o == mine && v < t)) r++;
        }
        rk[t] = r;          // sorted rank of hinge t (ties broken by index)
        ws[r] = mine;       // sorted hinge array
    }
    __syncthreads();

    if (t < H_DIM * NK) {
        int h = t / NK, k = t % NK;   // interval k: dist in (s[k-1], s[k])
        float A = 0.0f, B = b_out[h];
        for (int w = 0; w < W_DIM; w++) {
            float w1 = W_in[w], bv = b_in[w], ov = W_out[h * W_DIM + w];
            // relu(w1*d+bv) active on interval k?
            bool active = (w1 > 0.0f) ? (k > rk[w])
                        : (w1 < 0.0f) ? (k <= rk[w])
                        : (bv > 0.0f);
            if (active) { A += w1 * ov; B += bv * ov; }
        }
        ws[W_DIM + h * 2 * NK + 2 * k]     = A;
        ws[W_DIM + h * 2 * NK + 2 * k + 1] = B;
    }
}

// ---------------- main: wave-per-row, PWL evaluation ------------------------
__global__ __launch_bounds__(256) void cope_fire_kernel(
    const float* __restrict__ attn,   // (H*S, S)
    const float* __restrict__ c_p,
    const float* __restrict__ Lm_p,
    const float* __restrict__ iL_p,
    const float* __restrict__ ws,
    float* __restrict__ out)
{
    const int t    = threadIdx.x;
    const int lane = t & 63;
    const int wave = t >> 6;
    const int row  = blockIdx.x * 4 + wave;       // one wave per row
    const int h    = blockIdx.x / (S_DIM / 4);    // 192 blocks per h (uniform)

    __shared__ float sh[W_DIM];     // sorted hinges
    __shared__ float sAB[2 * NK];   // A,B pairs for this h

    if (t < W_DIM)  sh[t]  = ws[t];
    if (t < 2 * NK) sAB[t] = ws[W_DIM + h * 2 * NK + t];

    // uniform scalars (constant-index -> scalar loads)
    const float s3 = ws[3],  s7 = ws[7],  s11 = ws[11], s15 = ws[15];
    const float s19 = ws[19], s23 = ws[23], s27 = ws[27];
    const float c   = c_p[0];
    const float thr = fabsf(Lm_p[0] * iL_p[0]);

    // load 12 contiguous elements per lane (3x float4, 48B stride, all lines used)
    const float* rowp = attn + (size_t)row * S_DIM + lane * 12;
    float4 v0 = *(const float4*)(rowp);
    float4 v1 = *(const float4*)(rowp + 4);
    float4 v2 = *(const float4*)(rowp + 8);
    float g[12] = { v0.x, v0.y, v0.z, v0.w, v1.x, v1.y, v1.z, v1.w,
                    v2.x, v2.y, v2.z, v2.w };
#pragma unroll
    for (int i = 0; i < 12; i++)
        g[i] = __builtin_amdgcn_rcpf(1.0f + __expf(-g[i]));

    // lane total, inclusive wave scan over lane totals
    float T0 = 0.0f;
#pragma unroll
    for (int i = 0; i < 12; i++) T0 += g[i];
    float P = T0;
#pragma unroll
    for (int d = 1; d < 64; d <<= 1) {
        float y = __shfl_up(P, d, 64);
        if (lane >= d) P += y;
    }
    const float total = __shfl(P, 63, 64);
    const float base  = total - P + T0;   // suffix sum starting at lane's first elem

    const float den     = __logf(fabsf(c * fminf(total, thr)) + 1.0f) + EPS_F;
    const float inv_den = __builtin_amdgcn_rcpf(den);

    __syncthreads();   // tables staged

    float o[12];
    float e = 0.0f;
#pragma unroll
    for (int i = 0; i < 12; i++) {
        float pos = base - e;            // suffix sum at element i
        e += g[i];
        float d = __logf(fabsf(c * pos) + 1.0f) * inv_den;

        // lower_bound: k = #{hinges < d}, levels 16/8/4 via register selects
        int k = 0;
        bool b1 = (s15 < d);             if (b1) k += 16;
        float l2 = b1 ? s23 : s7;
        bool b2 = (l2 < d);              if (b2) k += 8;
        float l3a = b2 ? s11 : s3;
        float l3b = b2 ? s27 : s19;
        float l3  = b1 ? l3b : l3a;
        if (l3 < d) k += 4;
        // levels 2/1 + fixup via LDS
        if (sh[k + 1] < d) k += 2;
        if (sh[k]     < d) k += 1;
        if (sh[k]     < d) k += 1;       // final fixup -> k in [0,32]

        float2 ab = *(const float2*)(&sAB[2 * k]);
        o[i] = fmaf(d, ab.x, ab.y);      // A_k*dist + B_k (bo folded in)
    }

    float* op = out + (size_t)row * S_DIM + lane * 12;
    *(float4*)(op)     = make_float4(o[0], o[1], o[2],  o[3]);
    *(float4*)(op + 4) = make_float4(o[4], o[5], o[6],  o[7]);
    *(float4*)(op + 8) = make_float4(o[8], o[9], o[10], o[11]);
}

extern "C" void kernel_launch(void* const* d_in, const int* in_sizes, int n_in,
                              void* d_out, int out_size, void* d_ws, size_t ws_size,
                              hipStream_t stream) {
    const float* attn  = (const float*)d_in[0];
    const float* W_in  = (const float*)d_in[1];
    const float* b_in  = (const float*)d_in[2];
    const float* W_out = (const float*)d_in[3];
    const float* b_out = (const float*)d_in[4];
    const float* c_p   = (const float*)d_in[5];
    const float* Lm_p  = (const float*)d_in[6];
    const float* iL_p  = (const float*)d_in[7];
    float* out = (float*)d_out;
    float* ws  = (float*)d_ws;

    cope_setup_kernel<<<1, 512, 0, stream>>>(W_in, b_in, W_out, b_out, ws);

    const int rows = H_DIM * S_DIM;            // 9216 rows, one wave each
    cope_fire_kernel<<<rows / 4, 256, 0, stream>>>(
        attn, c_p, Lm_p, iL_p, ws, out);
}